// Round 1
// baseline (2126.322 us; speedup 1.0000x reference)
//
#include <hip/hip_runtime.h>
#include <hip/hip_bf16.h>
#include <cstdint>
#include <cstddef>

// Problem constants (TimeEmbedder): B=32768 rows, DIM=1024, HID=4096
#define NB   32768
#define DIM_ 1024
#define HID_ 4096

typedef __attribute__((ext_vector_type(4))) float floatx4;
typedef __attribute__((ext_vector_type(8))) short bf16x8;

__device__ __forceinline__ short f2bf(float v) {
  __hip_bfloat16 b = __float2bfloat16(v);   // RNE
  union { __hip_bfloat16 b; short s; } u; u.b = b; return u.s;
}

__device__ __forceinline__ void async_copy16(const short* g, short* l) {
  __builtin_amdgcn_global_load_lds(
      (const __attribute__((address_space(1))) void*)g,
      (__attribute__((address_space(3))) void*)l, 16, 0, 0);
}

// ---------------------------------------------------------------------------
// Kernel 1: positional embedding + layernorm (unbiased std), bf16 output.
// One wave per row; lane handles 8 freqs (8 cos + 8 sin outputs).
// ---------------------------------------------------------------------------
__global__ void embed_ln_kernel(const float* __restrict__ t, short* __restrict__ out) {
  const int lane = threadIdx.x & 63;
  const int row  = blockIdx.x * 4 + (threadIdx.x >> 6);
  const float x = t[row] * 1000.0f;             // TIME_SCALING
  // freq(f) = (1e-4)^(f/511) = 2^(log2(1e-4)/511 * f)
  const float kf = -0.026003341251564478f;      // log2(1e-4)/511
  float cv[8], sv[8];
  float sum = 0.f, sumsq = 0.f;
#pragma unroll
  for (int i = 0; i < 8; ++i) {
    const int f = lane * 8 + i;                 // 0..511
    const float freq = exp2f(kf * (float)f);
    const float ang  = x * freq;
    float s, c;
    sincosf(ang, &s, &c);
    cv[i] = c; sv[i] = s;
    sum   += c + s;
    sumsq += c * c + s * s;
  }
#pragma unroll
  for (int m = 1; m < 64; m <<= 1) {
    sum   += __shfl_xor(sum,   m, 64);
    sumsq += __shfl_xor(sumsq, m, 64);
  }
  const float mean = sum * (1.0f / 1024.0f);
  const float var  = (sumsq - sum * sum * (1.0f / 1024.0f)) * (1.0f / 1023.0f);
  const float rstd = rsqrtf(var);
  bf16x8 pc, ps;
#pragma unroll
  for (int i = 0; i < 8; ++i) {
    pc[i] = f2bf((cv[i] - mean) * rstd);
    ps[i] = f2bf((sv[i] - mean) * rstd);
  }
  *(bf16x8*)&out[(size_t)row * 1024 + lane * 8]       = pc;  // cos half
  *(bf16x8*)&out[(size_t)row * 1024 + 512 + lane * 8] = ps;  // sin half
}

// ---------------------------------------------------------------------------
// Kernel 2: transpose fp32 [R,C] -> bf16 [C,R] (tiled, coalesced both ways)
// block (32,8), each thread handles 4 rows of a 32x32 tile.
// ---------------------------------------------------------------------------
__global__ void transpose_f32_bf16(const float* __restrict__ in, short* __restrict__ out,
                                   int R, int C) {
  __shared__ float tile[32][33];                // +1 pad: no bank conflicts
  const int tx = threadIdx.x, ty = threadIdx.y;
  const int col0 = blockIdx.x * 32, row0 = blockIdx.y * 32;
#pragma unroll
  for (int j = 0; j < 4; ++j)
    tile[ty + 8 * j][tx] = in[(size_t)(row0 + ty + 8 * j) * C + col0 + tx];
  __syncthreads();
#pragma unroll
  for (int j = 0; j < 4; ++j)
    out[(size_t)(col0 + ty + 8 * j) * R + row0 + tx] = f2bf(tile[tx][ty + 8 * j]);
}

// ---------------------------------------------------------------------------
// Kernel 3/4: C = A[M,K] @ Bt[N,K]^T + bias, optional fused SiLU + bf16 out.
// m97 structure: 128x128 tile, BK=32, 4 waves (2x2), 4x4 mfma_16x16x32_bf16
// per wave, global_load_lds width=16 staging, 2-barrier K-loop.
// ---------------------------------------------------------------------------
template <bool SILU>
__global__ void gemm_bt(const short* __restrict__ A,   // [M,K] bf16
                        const short* __restrict__ Bt,  // [N,K] bf16
                        const float* __restrict__ bias,// [N] fp32
                        void* __restrict__ Cv,         // SILU: bf16 [M,N] else fp32
                        int K) {
  constexpr int N = HID_;
  __shared__ __align__(16) short As[128 * 32];  // 8 KB
  __shared__ __align__(16) short Bs[128 * 32];  // 8 KB

  const int tid  = threadIdx.x;
  const int lane = tid & 63;
  const int wave = tid >> 6;
  const int wr = (wave >> 1) * 64;   // wave row offset in tile
  const int wc = (wave & 1) * 64;    // wave col offset in tile
  const int row0 = blockIdx.y * 128;
  const int col0 = blockIdx.x * 128;

  floatx4 acc[4][4] = {};

  const short* Ag = A  + (size_t)row0 * K;
  const short* Bg = Bt + (size_t)col0 * K;

  const int ra = lane & 15;          // fragment row/col within 16
  const int ka = (lane >> 4) << 3;   // fragment k offset (0,8,16,24)

  for (int kt = 0; kt < K; kt += 32) {
    // stage 128x32 bf16 A and B tiles: 512 chunks of 16B each, 2/thread each
#pragma unroll
    for (int s = 0; s < 2; ++s) {
      const int c  = tid + s * 256;
      const int r  = c >> 2;
      const int k8 = (c & 3) << 3;
      async_copy16(Ag + (size_t)r * K + kt + k8, &As[c * 8]);
      async_copy16(Bg + (size_t)r * K + kt + k8, &Bs[c * 8]);
    }
    __syncthreads();

    bf16x8 a[4], b[4];
#pragma unroll
    for (int i = 0; i < 4; ++i)
      a[i] = *(const bf16x8*)&As[(wr + i * 16 + ra) * 32 + ka];
#pragma unroll
    for (int j = 0; j < 4; ++j)
      b[j] = *(const bf16x8*)&Bs[(wc + j * 16 + ra) * 32 + ka];
#pragma unroll
    for (int i = 0; i < 4; ++i)
#pragma unroll
      for (int j = 0; j < 4; ++j)
        acc[i][j] = __builtin_amdgcn_mfma_f32_16x16x32_bf16(a[i], b[j], acc[i][j], 0, 0, 0);
    __syncthreads();
  }

  // Epilogue. C/D layout (m89-verified): col = lane&15, row = (lane>>4)*4 + reg
  const int cc = lane & 15;
  const int cr = (lane >> 4) * 4;
  float bv[4];
#pragma unroll
  for (int j = 0; j < 4; ++j) bv[j] = bias[col0 + wc + j * 16 + cc];
#pragma unroll
  for (int i = 0; i < 4; ++i) {
#pragma unroll
    for (int j = 0; j < 4; ++j) {
      const int gc = col0 + wc + j * 16 + cc;
#pragma unroll
      for (int r = 0; r < 4; ++r) {
        const int gr = row0 + wr + i * 16 + cr + r;
        float v = acc[i][j][r] + bv[j];
        if constexpr (SILU) {
          v = v * (1.0f / (1.0f + __expf(-v)));
          ((short*)Cv)[(size_t)gr * N + gc] = f2bf(v);
        } else {
          ((float*)Cv)[(size_t)gr * N + gc] = v;
        }
      }
    }
  }
}

// ---------------------------------------------------------------------------
extern "C" void kernel_launch(void* const* d_in, const int* in_sizes, int n_in,
                              void* d_out, int out_size, void* d_ws, size_t ws_size,
                              hipStream_t stream) {
  const float* t  = (const float*)d_in[0];   // [32768]
  const float* W1 = (const float*)d_in[1];   // [1024,4096]
  const float* b1 = (const float*)d_in[2];   // [4096]
  const float* W2 = (const float*)d_in[3];   // [4096,4096]
  const float* b2 = (const float*)d_in[4];   // [4096]
  float* out = (float*)d_out;                // [32768,4096] fp32

  // workspace layout (all 16B aligned)
  char* ws = (char*)d_ws;
  short* timeN = (short*)(ws);                                          // 64 MB  [32768,1024] bf16
  short* W1t   = (short*)(ws + (size_t)67108864);                       // 8 MB   [4096,1024]  bf16
  short* W2t   = (short*)(ws + (size_t)67108864 + 8388608);             // 32 MB  [4096,4096]  bf16
  short* h     = (short*)(ws + (size_t)67108864 + 8388608 + 33554432);  // 256 MB [32768,4096] bf16

  embed_ln_kernel<<<NB / 4, 256, 0, stream>>>(t, timeN);
  transpose_f32_bf16<<<dim3(4096 / 32, 1024 / 32), dim3(32, 8), 0, stream>>>(W1, W1t, 1024, 4096);
  transpose_f32_bf16<<<dim3(4096 / 32, 4096 / 32), dim3(32, 8), 0, stream>>>(W2, W2t, 4096, 4096);
  gemm_bt<true ><<<dim3(HID_ / 128, NB / 128), 256, 0, stream>>>(timeN, W1t, b1, (void*)h,   DIM_);
  gemm_bt<false><<<dim3(HID_ / 128, NB / 128), 256, 0, stream>>>(h,     W2t, b2, (void*)out, HID_);
}